// Round 9
// baseline (174.240 us; speedup 1.0000x reference)
//
#include <hip/hip_runtime.h>
#include <hip/hip_bf16.h>

#define N_EMBD 1024
#define T_SEQ  2048
#define BATCH  2
#define NHEAD  16
#define DKH    64
#define MTOK   (BATCH * T_SEQ)   // 4096

typedef __attribute__((ext_vector_type(8))) short short8;   // 8 x bf16
typedef __attribute__((ext_vector_type(4))) short short4v;  // 4 x bf16
typedef __attribute__((ext_vector_type(4))) float floatx4;  // MFMA C/D

#define QSCALE 0.18033688011112042f   // 0.125 * log2(e), folded into Q

static __device__ __forceinline__ short bf16_of(float f) {
    union { float f; unsigned u; } x; x.f = f;
    unsigned r = (x.u + 0x7fff + ((x.u >> 16) & 1)) >> 16;
    return (short)r;
}

// Fragment-major layout for a row-major [R][1024] bf16 matrix:
//   elem (row, k) -> ((row>>4)*32 + (k>>5))*512 + (((k>>3)&3)*16 + (row&15))*8 + (k&7)
// One MFMA operand fragment (16 rows x 32 k) = 512 contiguous shorts,
// loadable as lane*16B fully-coalesced dwordx4.

// ---------------- fp32 -> bf16 fragment-major convert, all 5 tensors ----------------
__global__ __launch_bounds__(256) void cvt_frag(
    const float* __restrict__ x,  const float* __restrict__ Wq,
    const float* __restrict__ Wk, const float* __restrict__ Wv,
    const float* __restrict__ Wo,
    short* __restrict__ xf, short* __restrict__ wqkf,
    short* __restrict__ wvf, short* __restrict__ wof)
{
    int b = blockIdx.x;
    const float* src; short* dst; int srb, drb;
    if (b < 256)      { src = x;  dst = xf;   srb = b;       drb = srb; }
    else if (b < 320) { src = Wq; dst = wqkf; srb = b - 256; drb = srb; }
    else if (b < 384) { src = Wk; dst = wqkf; srb = b - 320; drb = srb + 64; }
    else if (b < 448) { src = Wv; dst = wvf;  srb = b - 384; drb = srb; }
    else              { src = Wo; dst = wof;  srb = b - 448; drb = srb; }

    const int row16 = threadIdx.x >> 4;          // 0..15
    const int kseg  = (threadIdx.x & 15) * 64;   // k base (64 elems per thread)
    const float* sp = src + ((long)srb * 16 + row16) * 1024 + kseg;
    short* dp       = dst + ((long)drb * 32 + (kseg >> 5)) * 512 + row16 * 8;

#pragma unroll
    for (int c = 0; c < 8; ++c) {
        float4 v0 = *(const float4*)(sp + c * 8);
        float4 v1 = *(const float4*)(sp + c * 8 + 4);
        short8 o;
        o[0] = bf16_of(v0.x); o[1] = bf16_of(v0.y); o[2] = bf16_of(v0.z); o[3] = bf16_of(v0.w);
        o[4] = bf16_of(v1.x); o[5] = bf16_of(v1.y); o[6] = bf16_of(v1.z); o[7] = bf16_of(v1.w);
        *(short8*)(dp + (c >> 2) * 512 + (c & 3) * 128) = o;
    }
}

// K-loop: per-wave 64x128 tile, register ping-pong prefetch, no LDS/barriers.
#define GEMM_KLOOP(Ab, Bb)                                                     \
    floatx4 acc[4][8] = {};                                                    \
    short8 a0[4], a1[4], b0[8], b1[8];                                         \
    _Pragma("unroll") for (int i = 0; i < 4; ++i)                              \
        a0[i] = *(const short8*)(Ab + (long)i * 32 * 512);                     \
    _Pragma("unroll") for (int j = 0; j < 8; ++j)                              \
        b0[j] = *(const short8*)(Bb + (long)j * 32 * 512);                     \
    for (int kc = 0; kc < 32; kc += 2) {                                       \
        _Pragma("unroll") for (int i = 0; i < 4; ++i)                          \
            a1[i] = *(const short8*)(Ab + ((long)i * 32 + kc + 1) * 512);      \
        _Pragma("unroll") for (int j = 0; j < 8; ++j)                          \
            b1[j] = *(const short8*)(Bb + ((long)j * 32 + kc + 1) * 512);      \
        _Pragma("unroll") for (int i = 0; i < 4; ++i)                          \
            _Pragma("unroll") for (int j = 0; j < 8; ++j)                      \
                acc[i][j] = __builtin_amdgcn_mfma_f32_16x16x32_bf16(           \
                    a0[i], b0[j], acc[i][j], 0, 0, 0);                         \
        if (kc + 2 < 32) {                                                     \
            _Pragma("unroll") for (int i = 0; i < 4; ++i)                      \
                a0[i] = *(const short8*)(Ab + ((long)i * 32 + kc + 2) * 512);  \
            _Pragma("unroll") for (int j = 0; j < 8; ++j)                      \
                b0[j] = *(const short8*)(Bb + ((long)j * 32 + kc + 2) * 512);  \
        }                                                                      \
        _Pragma("unroll") for (int i = 0; i < 4; ++i)                          \
            _Pragma("unroll") for (int j = 0; j < 8; ++j)                      \
                acc[i][j] = __builtin_amdgcn_mfma_f32_16x16x32_bf16(           \
                    a1[i], b1[j], acc[i][j], 0, 0, 0);                         \
    }

// ---------------- QKV GEMM: 1536 single-wave blocks, no LDS ----------------
// XCD swizzle (blk -> XCD is ~id%8): all m-blocks sharing one B token-tile get
// id%8 == n%8, so the shared 256KB B-tile stays in that XCD's L2; weights
// stream. QK path (ids [0,1024)): transposed, rows = Wqk feature, cols = token.
// V path (ids [1024,1536)): normal, rows = token, cols = Wv feature.
__global__ __launch_bounds__(64, 2) void gemm_qkv(
    const short* __restrict__ xf, const short* __restrict__ wqkf,
    const short* __restrict__ wvf,
    const float* __restrict__ bq, const float* __restrict__ bk, const float* __restrict__ bv,
    short* __restrict__ outQ, short* __restrict__ outK, short* __restrict__ outV)
{
    const int lane = threadIdx.x & 63;
    const int quad = lane >> 4, lr = lane & 15;
    const int wid  = blockIdx.x;
    const bool isQK = wid < 1024;
    int mw, nw;
    const short *Af, *Bf;
    if (isQK) {
        int xcd = wid & 7, rest = wid >> 3;
        int m = rest & 31, ng = rest >> 5;          // ng in [0,4)
        mw = m * 64; nw = (ng * 8 + xcd) * 128;     // token-tile n = ng*8+xcd
        Af = wqkf; Bf = xf;
    } else {
        int v = wid - 1024;                         // [0,512)
        mw = (v >> 3) * 64;                         // token rows
        nw = (v & 7) * 128;                         // Wv feature tile (id%8==n)
        Af = xf; Bf = wvf;
    }

    const short* Ab = Af + (long)(mw >> 4) * 32 * 512 + lane * 8;
    const short* Bb = Bf + (long)(nw >> 4) * 32 * 512 + lane * 8;

    GEMM_KLOOP(Ab, Bb)

    if (isQK) {
#pragma unroll
        for (int i = 0; i < 4; ++i) {
#pragma unroll
            for (int j = 0; j < 8; ++j) {
                int f0  = mw + i * 16 + quad * 4;      // feature of [Wq;Wk]
                int t   = nw + j * 16 + lr;            // global token
                int tb  = t & 2047;
                int sel = f0 >> 10;                    // 0=Q, 1=K
                int fb  = f0 & 1023;
                int h   = fb >> 6, d0 = fb & 63;
                long bh = (long)(t >> 11) * NHEAD + h;
                float4 bias = *(const float4*)((sel ? bk : bq) + fb);
                short4v y;
#pragma unroll
                for (int r = 0; r < 4; ++r) {
                    float v = acc[i][j][r] + (&bias.x)[r];
                    if (sel == 0) v *= QSCALE;
                    y[r] = bf16_of(v);
                }
                long idx = ((bh * 128 + (tb >> 4)) * 2 + (d0 >> 5)) * 512
                         + (((d0 >> 3) & 3) * 16 + (tb & 15)) * 8 + (d0 & 7);
                *(short4v*)((sel ? outK : outQ) + idx) = y;
            }
        }
    } else {
#pragma unroll
        for (int i = 0; i < 4; ++i) {
#pragma unroll
            for (int j = 0; j < 8; ++j) {
                int t0 = mw + i * 16 + quad * 4;       // global token base
                int tb = t0 & 2047;
                int d  = nw + j * 16 + lr;             // Wv feature
                int h  = d >> 6, dblk = (d >> 4) & 3;
                long bh = (long)(t0 >> 11) * NHEAD + h;
                float bias = bv[d];
                short4v y;
#pragma unroll
                for (int r = 0; r < 4; ++r) y[r] = bf16_of(acc[i][j][r] + bias);
                long idx = ((bh * 64 + (tb >> 5)) * 4 + dblk) * 512
                         + lane * 8 + (i & 1) * 4;
                *(short4v*)(outV + idx) = y;
            }
        }
    }
}

// ---------------- output projection: 512 single-wave blocks, no LDS ----------------
// Transposed (rows = out-feature 64, cols = token 128); float4 stores.
// XCD swizzle: id%8 == token-tile%8 (share Yf tile via per-XCD L2).
__global__ __launch_bounds__(64, 2) void gemm_proj(
    const short* __restrict__ Yf, const short* __restrict__ wof,
    const float* __restrict__ bo, float* __restrict__ out)
{
    const int lane = threadIdx.x & 63;
    const int quad = lane >> 4, lr = lane & 15;
    const int wid  = blockIdx.x;
    const int xcd  = wid & 7, rest = wid >> 3;
    const int m    = rest & 15, ng = rest >> 4;   // ng in [0,4)
    const int mw   = m * 64;                      // out-feature
    const int nw   = (ng * 8 + xcd) * 128;        // token

    const short* Ab = wof + (long)(mw >> 4) * 32 * 512 + lane * 8;
    const short* Bb = Yf  + (long)(nw >> 4) * 32 * 512 + lane * 8;

    GEMM_KLOOP(Ab, Bb)

#pragma unroll
    for (int i = 0; i < 4; ++i) {
#pragma unroll
        for (int j = 0; j < 8; ++j) {
            int  f0 = mw + i * 16 + quad * 4;
            long t  = nw + j * 16 + lr;
            float4 b4 = *(const float4*)(bo + f0);
            float4 o4;
            o4.x = acc[i][j][0] + b4.x;
            o4.y = acc[i][j][1] + b4.y;
            o4.z = acc[i][j][2] + b4.z;
            o4.w = acc[i][j][3] + b4.w;
            *(float4*)(out + t * N_EMBD + f0) = o4;
        }
    }
}

// ---------------- flash attention; epilogue -> fragment-major Y ----------------
// id%8 == bh%8: same-bh q-tiles share K/V/Q via per-XCD L2 (already local).
__global__ __launch_bounds__(256) void attn_kernel(
    const short* __restrict__ Qf, const short* __restrict__ Kf,
    const short* __restrict__ Vf, short* __restrict__ Y)
{
    __shared__ float Ob[2][32][68];
    __shared__ float Lb[2][32];

    const int tid  = threadIdx.x;
    const int w    = tid >> 6, lane = tid & 63;
    const int quad = lane >> 4, lr = lane & 15;
    const int qs   = w & 1, half = w >> 1;

    const int id = blockIdx.x;
    const int qt = 31 - (id >> 5);
    const int bh = id & 31;

    const short* Qp = Qf + (long)bh * 131072;
    const short* Kp = Kf + (long)bh * 131072;
    const short* Vp = Vf + (long)bh * 131072;

    const int qrb = qt * 64 + qs * 32;
    const int qb  = qrb >> 4;

    short8 qfv[2][2];
#pragma unroll
    for (int m = 0; m < 2; ++m)
#pragma unroll
        for (int c = 0; c < 2; ++c)
            qfv[m][c] = *(const short8*)(Qp + (long)(((qb + m) * 2 + c) * 512) + lane * 8);

    floatx4 o[2][4] = {};
    float rs[2] = {0.f, 0.f};

    const int S_tot = 2 * qt + qs + 1;
    const int h0 = (S_tot + 1) >> 1;
    const int sb = half ? h0 : 0;
    const int se = half ? S_tot : h0;

    short8 kbn[2][2];
    if (sb < se) {
#pragma unroll
        for (int blk = 0; blk < 2; ++blk)
#pragma unroll
            for (int c = 0; c < 2; ++c)
                kbn[blk][c] = *(const short8*)(Kp + (long)(((sb * 2 + blk) * 2 + c) * 512) + lane * 8);
    }

    for (int s = sb; s < se; ++s) {
        short8 ka[2][2];
#pragma unroll
        for (int blk = 0; blk < 2; ++blk)
#pragma unroll
            for (int c = 0; c < 2; ++c) ka[blk][c] = kbn[blk][c];
        if (s + 1 < se) {
#pragma unroll
            for (int blk = 0; blk < 2; ++blk)
#pragma unroll
                for (int c = 0; c < 2; ++c)
                    kbn[blk][c] = *(const short8*)(Kp + (long)((((s + 1) * 2 + blk) * 2 + c) * 512) + lane * 8);
        }
        short8 va[4];
#pragma unroll
        for (int d = 0; d < 4; ++d)
            va[d] = *(const short8*)(Vp + (long)((s * 4 + d) * 512) + lane * 8);

        floatx4 sc[2][2];
#pragma unroll
        for (int m = 0; m < 2; ++m)
#pragma unroll
            for (int blk = 0; blk < 2; ++blk) {
                floatx4 z = {};
                z = __builtin_amdgcn_mfma_f32_16x16x32_bf16(ka[blk][0], qfv[m][0], z, 0, 0, 0);
                z = __builtin_amdgcn_mfma_f32_16x16x32_bf16(ka[blk][1], qfv[m][1], z, 0, 0, 0);
                sc[m][blk] = z;
            }

        if (s == S_tot - 1) {
            const int k0 = s * 32;
#pragma unroll
            for (int m = 0; m < 2; ++m)
#pragma unroll
                for (int blk = 0; blk < 2; ++blk)
#pragma unroll
                    for (int r = 0; r < 4; ++r) {
                        int key = k0 + blk * 16 + quad * 4 + r;
                        if (key > qrb + m * 16 + lr) sc[m][blk][r] = -INFINITY;
                    }
        }

        // P = exp2(S^T), TRUNCATING bf16 pack (P in [0,1]; bias << threshold)
        short8 pa[2];
#pragma unroll
        for (int m = 0; m < 2; ++m) {
            union { short8 v; short e[8]; } pu;
#pragma unroll
            for (int blk = 0; blk < 2; ++blk)
#pragma unroll
                for (int r = 0; r < 4; ++r) {
                    float p = __builtin_amdgcn_exp2f(sc[m][blk][r]);
                    rs[m] += p;
                    union { float f; unsigned u; } cc; cc.f = p;
                    pu.e[blk * 4 + r] = (short)(cc.u >> 16);
                }
            pa[m] = pu.v;
        }

#pragma unroll
        for (int m = 0; m < 2; ++m)
#pragma unroll
            for (int d = 0; d < 4; ++d)
                o[m][d] = __builtin_amdgcn_mfma_f32_16x16x32_bf16(va[d], pa[m], o[m][d], 0, 0, 0);
    }

#pragma unroll
    for (int m = 0; m < 2; ++m) {
        rs[m] += __shfl_xor(rs[m], 16, 64);
        rs[m] += __shfl_xor(rs[m], 32, 64);
    }

    if (half == 1) {
#pragma unroll
        for (int m = 0; m < 2; ++m) {
#pragma unroll
            for (int d = 0; d < 4; ++d)
                *(floatx4*)&Ob[qs][m * 16 + lr][d * 16 + quad * 4] = o[m][d];
            Lb[qs][m * 16 + lr] = rs[m];
        }
    }
    __syncthreads();
    if (half == 0) {
        // write Y fragment-major over GLOBAL tokens: rowblk = (bh>>4)*128 + qb + m
        const long rb0 = (long)(bh >> 4) * 128 + qb;
        const int  hk  = (bh & 15) * DKH;
#pragma unroll
        for (int m = 0; m < 2; ++m) {
            float l   = rs[m] + Lb[qs][m * 16 + lr];
            float inv = 1.f / l;
            long  rb  = rb0 + m;
#pragma unroll
            for (int d = 0; d < 4; ++d) {
                floatx4 ob = *(const floatx4*)&Ob[qs][m * 16 + lr][d * 16 + quad * 4];
                short4v y4;
#pragma unroll
                for (int r = 0; r < 4; ++r) y4[r] = bf16_of((o[m][d][r] + ob[r]) * inv);
                int kb = hk + d * 16 + quad * 4;
                long idx = (rb * 32 + (kb >> 5)) * 512
                         + (((kb >> 3) & 3) * 16 + lr) * 8 + (quad & 1) * 4;
                *(short4v*)(Y + idx) = y4;
            }
        }
    }
}

extern "C" void kernel_launch(void* const* d_in, const int* in_sizes, int n_in,
                              void* d_out, int out_size, void* d_ws, size_t ws_size,
                              hipStream_t stream) {
    const float* x  = (const float*)d_in[0];
    const float* Wq = (const float*)d_in[1];
    const float* bq = (const float*)d_in[2];
    const float* Wk = (const float*)d_in[3];
    const float* bk = (const float*)d_in[4];
    const float* Wv = (const float*)d_in[5];
    const float* bv = (const float*)d_in[6];
    const float* Wo = (const float*)d_in[7];
    const float* bo = (const float*)d_in[8];
    float* out = (float*)d_out;

    char* ws = (char*)d_ws;
    short* xf   = (short*)(ws);                      // x frag-major, 8MB; reused as Yf
    short* wqkf = (short*)(ws + (8L  << 20));        // [Wq;Wk] frag-major, 4MB
    short* wvf  = (short*)(ws + (12L << 20));        // Wv frag-major, 2MB
    short* wof  = (short*)(ws + (14L << 20));        // Wo frag-major, 2MB
    short* Qb   = (short*)(ws + (16L << 20));        // Qf, 8MB (pre-scaled)
    short* Kbuf = (short*)(ws + (24L << 20));        // Kf, 8MB
    short* Vtb  = (short*)(ws + (32L << 20));        // Vf, 8MB
    short* Yf   = xf;                                // reuse (x dead after QKV GEMM)

    cvt_frag<<<512, 256, 0, stream>>>(x, Wq, Wk, Wv, Wo, xf, wqkf, wvf, wof);

    gemm_qkv<<<1536, 64, 0, stream>>>(xf, wqkf, wvf, bq, bk, bv, Qb, Kbuf, Vtb);
    attn_kernel<<<1024, 256, 0, stream>>>(Qb, Kbuf, Vtb, Yf);
    gemm_proj<<<512, 64, 0, stream>>>(Yf, wof, bo, out);
}